// Round 17
// baseline (18.678 us; speedup 1.0000x reference)
//
#include <hip/hip_runtime.h>

// Problem constants: B=16, T=64, N=128, D=512, H=512, O=256, A=18
#define DD 512
#define HH 512
#define OO 256
#define AA 18
#define ROWS 1024

typedef __attribute__((ext_vector_type(8))) short bf16x8;
typedef __attribute__((ext_vector_type(4))) float f32x4;

// f32 -> bf16 round-to-nearest-even (bit trick; inputs are finite).
__device__ __forceinline__ unsigned short f2bf(float x) {
  unsigned u = __builtin_bit_cast(unsigned, x);
  u += 0x7FFFu + ((u >> 16) & 1u);
  return (unsigned short)(u >> 16);
}

// ---------------------------------------------------------------------------
// k1: U(bf16) = pathGCN1(obs @ W1). Tile 64x32 (64 rows == one batch ->
// t == local row). 512 thr = 2 K-groups x 4 waves; each group K=256 as
// 2 chunks of BK=128 (staging barriers 7->3 vs r15). B-staging via coalesced
// float4-across-n loads (4/thread/chunk, was 8 strided scalars) + scattered
// bf16 LDS stores. K-accumulation order unchanged vs r15 -> absmax must be
// bit-identical. Merge via split Gs planes + plain stores (no LDS atomics).
// Prologue chores: zero out-slice + one W2 row -> bf16 W2t.
// Grid: 16 ct x 16 rt = 256 blocks. LDS = 69 KB.
// ---------------------------------------------------------------------------
__global__ __launch_bounds__(512) void k1_mfma_combine(
    const float* __restrict__ obs, const float* __restrict__ W1,
    const float* __restrict__ b1, const float* __restrict__ W2,
    unsigned short* __restrict__ U, unsigned short* __restrict__ W2t,
    float* __restrict__ out) {
  __shared__ unsigned short As[2][64][136];
  __shared__ unsigned short Bt[2][32][136];
  __shared__ float Gs[2][64][36];

  const int tid = threadIdx.x;
  const int blk = blockIdx.x;
  const int g = tid >> 8;              // K-group
  const int gt = tid & 255;
  const int lane = tid & 63;
  const int wid = (tid >> 6) & 3;      // wave within group
  const int col0 = (blk & 15) * 32;
  const int row0 = (blk >> 4) * 64;
  const int k0 = g * 256;

  // Prologue chore 1: zero out slice (256 blocks x 72 = 18432 = 1024*18).
  if (tid < 72) out[blk * 72 + tid] = 0.f;
  // Prologue chore 2: W2t[n=blk][k=tid] = bf16(W2[k][n]).
  W2t[(size_t)blk * HH + tid] = f2bf(W2[(size_t)tid * OO + blk]);

  const int sar = gt >> 2, saq = (gt & 3) * 32;   // A: row, k-offset (32 k)
  const int bn4 = gt & 7, bk0 = gt >> 3;          // B: float4 n-slot, base k
  const int lr = lane & 15, lk = (lane >> 4) * 8; // fragment indices

  float4 pa[8], pb[4];
  f32x4 acc0 = {0.f, 0.f, 0.f, 0.f}, acc1 = {0.f, 0.f, 0.f, 0.f};

#define LOADG(kb)                                                              \
  {                                                                            \
    const float* Ap = &obs[(size_t)(row0 + sar) * DD + (kb) + saq];            \
    _Pragma("unroll") for (int q = 0; q < 8; ++q)                              \
        pa[q] = *reinterpret_cast<const float4*>(Ap + q * 4);                  \
    _Pragma("unroll") for (int q = 0; q < 4; ++q)                              \
        pb[q] = *reinterpret_cast<const float4*>(                              \
            &W1[(size_t)((kb) + bk0 + q * 32) * HH + col0 + bn4 * 4]);         \
  }
#define STOLDS()                                                               \
  {                                                                            \
    _Pragma("unroll") for (int q = 0; q < 4; ++q) {                            \
      bf16x8 v;                                                                \
      v[0] = (short)f2bf(pa[2 * q].x);     v[1] = (short)f2bf(pa[2 * q].y);    \
      v[2] = (short)f2bf(pa[2 * q].z);     v[3] = (short)f2bf(pa[2 * q].w);    \
      v[4] = (short)f2bf(pa[2 * q + 1].x); v[5] = (short)f2bf(pa[2 * q + 1].y);\
      v[6] = (short)f2bf(pa[2 * q + 1].z); v[7] = (short)f2bf(pa[2 * q + 1].w);\
      *reinterpret_cast<bf16x8*>(&As[g][sar][saq + q * 8]) = v;                \
    }                                                                          \
    _Pragma("unroll") for (int q = 0; q < 4; ++q) {                            \
      const int bk = bk0 + q * 32;                                             \
      Bt[g][bn4 * 4 + 0][bk] = f2bf(pb[q].x);                                  \
      Bt[g][bn4 * 4 + 1][bk] = f2bf(pb[q].y);                                  \
      Bt[g][bn4 * 4 + 2][bk] = f2bf(pb[q].z);                                  \
      Bt[g][bn4 * 4 + 3][bk] = f2bf(pb[q].w);                                  \
    }                                                                          \
  }
#define COMPUTE()                                                              \
  {                                                                            \
    _Pragma("unroll") for (int ks = 0; ks < 4; ++ks) {                         \
      const bf16x8 af =                                                        \
          *reinterpret_cast<const bf16x8*>(&As[g][wid * 16 + lr][ks * 32 + lk]); \
      const bf16x8 bf0 =                                                       \
          *reinterpret_cast<const bf16x8*>(&Bt[g][lr][ks * 32 + lk]);          \
      const bf16x8 bf1 =                                                       \
          *reinterpret_cast<const bf16x8*>(&Bt[g][16 + lr][ks * 32 + lk]);     \
      acc0 = __builtin_amdgcn_mfma_f32_16x16x32_bf16(af, bf0, acc0, 0, 0, 0);  \
      acc1 = __builtin_amdgcn_mfma_f32_16x16x32_bf16(af, bf1, acc1, 0, 0, 0);  \
    }                                                                          \
  }

  // 2 chunks of BK=128 per K-group: 3 staging barriers.
  LOADG(k0);
  STOLDS();
  __syncthreads();
  LOADG(k0 + 128);
  COMPUTE();
  __syncthreads();
  STOLDS();
  __syncthreads();
  COMPUTE();
  __syncthreads();
#undef LOADG
#undef STOLDS
#undef COMPUTE

  // K-group partials -> split Gs planes, plain disjoint stores (no atomics).
  // C/D layout: col = lane&15, row = (lane>>4)*4 + reg.
  {
    const int crow = wid * 16 + (lane >> 4) * 4;
#pragma unroll
    for (int i = 0; i < 4; ++i) Gs[g][crow + i][lr] = acc0[i];
#pragma unroll
    for (int i = 0; i < 4; ++i) Gs[g][crow + i][16 + lr] = acc1[i];
  }
  __syncthreads();

  // Path-GCN layer-1 combine -> U (bf16). t == local row (tile == one batch).
  {
    const int rr = tid >> 3;
    const int c4 = (tid & 7) * 4;
    const int t = rr;
    const float is6 = 0.4082482904638630f;  // 1/sqrt(6)
    float c0, c1, c2, d1, d2, al, be;
    if (t <= 1) {
      c0 = 0.f; c1 = 0.f; c2 = 1.f; d1 = 0.f; d2 = 0.f; al = 1.f; be = 0.f;
    } else if (t == 2) {
      c0 = 0.f; c1 = 0.5f; c2 = 0.5f; d1 = 0.5f; d2 = 0.5f; al = 0.5f; be = 0.5f;
    } else {
      c0 = (t == 3) ? is6 : (1.f / 3.f);
      c1 = 1.f / 3.f; c2 = is6;
      d1 = is6; d2 = 0.5f;
      al = is6; be = 0.5f;
    }
    const int rm1 = (t >= 1) ? rr - 1 : rr;
    const int rm2 = (t >= 2) ? rr - 2 : rr;
    ushort4 uo;
    unsigned short* up = (unsigned short*)&uo;
#pragma unroll
    for (int j = 0; j < 4; ++j) {
      const int c = c4 + j;
      const float gc = Gs[0][rr][c] + Gs[1][rr][c];
      const float gb = Gs[0][rm1][c] + Gs[1][rm1][c];
      const float ga = Gs[0][rm2][c] + Gs[1][rm2][c];
      const float bb = b1[col0 + c];
      const float h1a = fmaxf(c0 * ga + c1 * gb + c2 * gc + bb, 0.f);
      const float h1b = fmaxf(d1 * gb + d2 * gc + bb, 0.f);
      up[j] = f2bf(al * h1a + be * h1b);
    }
    *reinterpret_cast<ushort4*>(&U[(size_t)(row0 + rr) * HH + col0 + c4]) = uo;
  }
}

// ---------------------------------------------------------------------------
// k2 [r16-verbatim, best measured]: fused GEMM2 + head, single staging round.
// 512 thr = 4 K-groups x 2 waves; group kg owns K-slice kg*128 as ONE chunk.
// Merge via 4 split tg planes + plain stores. Per block (ct 0..7, rt 0..31):
// tgt tile 32x32 = relu(sum planes + b2); head partial atomicAdd into out
// (zeroed by k1; bl added by ct==0). LDS = 94.9 KB.
// ---------------------------------------------------------------------------
__global__ __launch_bounds__(512) void k2_fused_head(
    const unsigned short* __restrict__ U, const unsigned short* __restrict__ W2t,
    const float* __restrict__ b2, const float* __restrict__ Wl,
    const float* __restrict__ bl, float* __restrict__ out) {
  __shared__ unsigned short As2[4][32][136];
  __shared__ unsigned short Bt2[4][32][136];
  __shared__ float tg[4][32][36];
  __shared__ float tgs[32][36];
  __shared__ float sWl[32][18];

  const int tid = threadIdx.x;
  const int lane = tid & 63;
  const int w = tid >> 6;
  const int kg = w >> 1;               // K-group 0..3
  const int wg = w & 1;                // wave in group: row-half
  const int gt = tid & 127;
  const int ct = blockIdx.x & 7;
  const int col0 = ct * 32;
  const int r0 = (blockIdx.x >> 3) * 32;
  const int lr = lane & 15, lk = (lane >> 4) * 8;
  const int k0 = kg * 128;

  const int sar = gt >> 2, sak = (gt & 3) * 32;

  // Stage Wl col-slice early (overlaps with global load latency).
  for (int i = tid; i < 32 * AA; i += 512) {
    const int n = i / AA, o = i - n * AA;
    sWl[n][o] = Wl[(size_t)(col0 + n) * AA + o];
  }

  // One staging round: 8 x bf16x8 global loads, all in flight together.
  bf16x8 pa[4], pb[4];
  {
    const unsigned short* Ap = &U[(size_t)(r0 + sar) * HH + k0 + sak];
#pragma unroll
    for (int q = 0; q < 4; ++q) pa[q] = *reinterpret_cast<const bf16x8*>(Ap + q * 8);
    const unsigned short* Bp = &W2t[(size_t)(col0 + sar) * HH + k0 + sak];
#pragma unroll
    for (int q = 0; q < 4; ++q) pb[q] = *reinterpret_cast<const bf16x8*>(Bp + q * 8);
  }
#pragma unroll
  for (int q = 0; q < 4; ++q)
    *reinterpret_cast<bf16x8*>(&As2[kg][sar][sak + q * 8]) = pa[q];
#pragma unroll
  for (int q = 0; q < 4; ++q)
    *reinterpret_cast<bf16x8*>(&Bt2[kg][sar][sak + q * 8]) = pb[q];
  __syncthreads();

  // Compute: wave (kg, wg) -> rows wg*16..+15, cols 0-15 (acc0) & 16-31 (acc1).
  f32x4 acc0 = {0.f, 0.f, 0.f, 0.f}, acc1 = {0.f, 0.f, 0.f, 0.f};
#pragma unroll
  for (int ks = 0; ks < 4; ++ks) {
    const bf16x8 af = *reinterpret_cast<const bf16x8*>(&As2[kg][wg * 16 + lr][ks * 32 + lk]);
    const bf16x8 bf0 = *reinterpret_cast<const bf16x8*>(&Bt2[kg][lr][ks * 32 + lk]);
    const bf16x8 bf1 = *reinterpret_cast<const bf16x8*>(&Bt2[kg][16 + lr][ks * 32 + lk]);
    acc0 = __builtin_amdgcn_mfma_f32_16x16x32_bf16(af, bf0, acc0, 0, 0, 0);
    acc1 = __builtin_amdgcn_mfma_f32_16x16x32_bf16(af, bf1, acc1, 0, 0, 0);
  }

  // Plane write: plain disjoint stores (C/D: col=lane&15, row=(lane>>4)*4+i).
  {
    const int crow = wg * 16 + (lane >> 4) * 4;
#pragma unroll
    for (int i = 0; i < 4; ++i) {
      tg[kg][crow + i][lr] = acc0[i];
      tg[kg][crow + i][16 + lr] = acc1[i];
    }
  }
  __syncthreads();

  // Sum 4 planes + b2 + relu -> tgs.
  for (int i = tid; i < 32 * 32; i += 512) {
    const int r = i >> 5, c = i & 31;
    const float s = tg[0][r][c] + tg[1][r][c] + tg[2][r][c] + tg[3][r][c]
                    + b2[col0 + c];
    tgs[r][c] = fmaxf(s, 0.f);
  }
  __syncthreads();

  // Head partial: out[r0+r][o] += sum_n tgs[r][n] * sWl[n][o] (+bl if ct==0).
  for (int p = tid; p < 32 * AA; p += 512) {
    const int r = p / AA, o = p - r * AA;
    float s = (ct == 0) ? bl[o] : 0.f;
#pragma unroll 8
    for (int n = 0; n < 32; ++n) s = fmaf(tgs[r][n], sWl[n][o], s);
    atomicAdd(&out[(size_t)(r0 + r) * AA + o], s);
  }
}

extern "C" void kernel_launch(void* const* d_in, const int* in_sizes, int n_in,
                              void* d_out, int out_size, void* d_ws, size_t ws_size,
                              hipStream_t stream) {
  const float* obs = (const float*)d_in[0];   // [1024, 512]
  const float* W1 = (const float*)d_in[4];    // [512, 512]
  const float* b1 = (const float*)d_in[5];    // [512]
  const float* W2 = (const float*)d_in[6];    // [512, 256]
  const float* b2 = (const float*)d_in[7];    // [256]
  const float* Wl = (const float*)d_in[8];    // [256, 18]
  const float* bl = (const float*)d_in[9];    // [18]
  float* out = (float*)d_out;                 // [1024, 18]

  unsigned short* U = (unsigned short*)d_ws;          // 1024x512 bf16 = 1 MiB
  unsigned short* W2t = U + (size_t)ROWS * HH;        // 256x512 bf16 = 256 KiB

  // 1) U = pathGCN1(obs @ W1) + {zero out, W2->W2t bf16}. 256 blocks.
  k1_mfma_combine<<<256, 512, 0, stream>>>(obs, W1, b1, W2, U, W2t, out);

  // 2) GEMM2 (4 K-groups, single staging round) + fused head. 256 blocks.
  k2_fused_head<<<256, 512, 0, stream>>>(U, W2t, b2, Wl, bl, out);
}

// Round 18
// 16.685 us; speedup vs baseline: 1.1194x; 1.1194x over previous
//
#include <hip/hip_runtime.h>

// Problem constants: B=16, T=64, N=128, D=512, H=512, O=256, A=18
#define DD 512
#define HH 512
#define OO 256
#define AA 18
#define ROWS 1024

typedef __attribute__((ext_vector_type(8))) short bf16x8;
typedef __attribute__((ext_vector_type(4))) float f32x4;

// f32 -> bf16 round-to-nearest-even (bit trick; inputs are finite).
__device__ __forceinline__ unsigned short f2bf(float x) {
  unsigned u = __builtin_bit_cast(unsigned, x);
  u += 0x7FFFu + ((u >> 16) & 1u);
  return (unsigned short)(u >> 16);
}

// ---------------------------------------------------------------------------
// k1: U(bf16) = pathGCN1(obs @ W1). r15-proven staging (BK=64, 4 chunks per
// K-group) + 2-buffer ping-pong with COMPILE-TIME buffer indices: 1 barrier
// per chunk (4 total, was 7). K-accumulation order unchanged -> absmax must
// stay bit-identical. Tile 64x32 (64 rows == one batch -> t == local row).
// 512 thr = 2 K-groups x 4 waves. Merge via split Gs planes + plain stores.
// Prologue chores: zero out-slice + one W2 row -> bf16 W2t.
// Grid: 16 ct x 16 rt = 256 blocks. LDS = 72 KB (1 block/CU, grid == CUs).
// ---------------------------------------------------------------------------
__global__ __launch_bounds__(512) void k1_mfma_combine(
    const float* __restrict__ obs, const float* __restrict__ W1,
    const float* __restrict__ b1, const float* __restrict__ W2,
    unsigned short* __restrict__ U, unsigned short* __restrict__ W2t,
    float* __restrict__ out) {
  __shared__ unsigned short As[2][2][64][72];   // [K-group][buf][row][k]
  __shared__ unsigned short Bt[2][2][32][72];   // [K-group][buf][col][k]
  __shared__ float Gs[2][64][36];

  const int tid = threadIdx.x;
  const int blk = blockIdx.x;
  const int g = tid >> 8;              // K-group
  const int gt = tid & 255;
  const int lane = tid & 63;
  const int wid = (tid >> 6) & 3;      // wave within group
  const int col0 = (blk & 15) * 32;
  const int row0 = (blk >> 4) * 64;
  const int k0 = g * 256;

  // Prologue chore 1: zero out slice (256 blocks x 72 = 18432 = 1024*18).
  if (tid < 72) out[blk * 72 + tid] = 0.f;
  // Prologue chore 2: W2t[n=blk][k=tid] = bf16(W2[k][n]).
  W2t[(size_t)blk * HH + tid] = f2bf(W2[(size_t)tid * OO + blk]);

  const int sar = gt >> 2, sak = (gt & 3) * 16;   // A staging: row, k-ofs
  const int sbc = gt & 31, sbk = (gt >> 5) * 8;   // B staging: col, k-ofs
  const int lr = lane & 15, lk = (lane >> 4) * 8; // fragment indices

  float4 pa0, pa1, pa2, pa3;
  float pb0, pb1, pb2, pb3, pb4, pb5, pb6, pb7;
  f32x4 acc0 = {0.f, 0.f, 0.f, 0.f}, acc1 = {0.f, 0.f, 0.f, 0.f};

#define LOADG(kb)                                                              \
  {                                                                            \
    const float* Ap = &obs[(size_t)(row0 + sar) * DD + (kb) + sak];            \
    pa0 = *reinterpret_cast<const float4*>(Ap);                                \
    pa1 = *reinterpret_cast<const float4*>(Ap + 4);                            \
    pa2 = *reinterpret_cast<const float4*>(Ap + 8);                            \
    pa3 = *reinterpret_cast<const float4*>(Ap + 12);                           \
    const float* Bp = &W1[(size_t)((kb) + sbk) * HH + col0 + sbc];             \
    pb0 = Bp[0]; pb1 = Bp[HH]; pb2 = Bp[2 * HH]; pb3 = Bp[3 * HH];             \
    pb4 = Bp[4 * HH]; pb5 = Bp[5 * HH]; pb6 = Bp[6 * HH]; pb7 = Bp[7 * HH];    \
  }
#define STOLDS(buf)                                                            \
  {                                                                            \
    bf16x8 v0, v1;                                                             \
    v0[0] = (short)f2bf(pa0.x); v0[1] = (short)f2bf(pa0.y);                    \
    v0[2] = (short)f2bf(pa0.z); v0[3] = (short)f2bf(pa0.w);                    \
    v0[4] = (short)f2bf(pa1.x); v0[5] = (short)f2bf(pa1.y);                    \
    v0[6] = (short)f2bf(pa1.z); v0[7] = (short)f2bf(pa1.w);                    \
    v1[0] = (short)f2bf(pa2.x); v1[1] = (short)f2bf(pa2.y);                    \
    v1[2] = (short)f2bf(pa2.z); v1[3] = (short)f2bf(pa2.w);                    \
    v1[4] = (short)f2bf(pa3.x); v1[5] = (short)f2bf(pa3.y);                    \
    v1[6] = (short)f2bf(pa3.z); v1[7] = (short)f2bf(pa3.w);                    \
    *reinterpret_cast<bf16x8*>(&As[g][buf][sar][sak]) = v0;                    \
    *reinterpret_cast<bf16x8*>(&As[g][buf][sar][sak + 8]) = v1;                \
    bf16x8 w;                                                                  \
    w[0] = (short)f2bf(pb0); w[1] = (short)f2bf(pb1);                          \
    w[2] = (short)f2bf(pb2); w[3] = (short)f2bf(pb3);                          \
    w[4] = (short)f2bf(pb4); w[5] = (short)f2bf(pb5);                          \
    w[6] = (short)f2bf(pb6); w[7] = (short)f2bf(pb7);                          \
    *reinterpret_cast<bf16x8*>(&Bt[g][buf][sbc][sbk]) = w;                     \
  }
#define COMPUTE(buf)                                                           \
  {                                                                            \
    _Pragma("unroll") for (int ks = 0; ks < 2; ++ks) {                         \
      const bf16x8 af = *reinterpret_cast<const bf16x8*>(                      \
          &As[g][buf][wid * 16 + lr][ks * 32 + lk]);                           \
      const bf16x8 bf0 = *reinterpret_cast<const bf16x8*>(                     \
          &Bt[g][buf][lr][ks * 32 + lk]);                                      \
      const bf16x8 bf1 = *reinterpret_cast<const bf16x8*>(                     \
          &Bt[g][buf][16 + lr][ks * 32 + lk]);                                 \
      acc0 = __builtin_amdgcn_mfma_f32_16x16x32_bf16(af, bf0, acc0, 0, 0, 0);  \
      acc1 = __builtin_amdgcn_mfma_f32_16x16x32_bf16(af, bf1, acc1, 0, 0, 0);  \
    }                                                                          \
  }

  // Ping-pong schedule, fully unrolled, compile-time buffer indices.
  // Chunk c -> buffer c&1. One barrier per chunk (4 total).
  LOADG(k0);
  STOLDS(0);
  __syncthreads();
  LOADG(k0 + 64);
  COMPUTE(0);
  STOLDS(1);
  __syncthreads();
  LOADG(k0 + 128);
  COMPUTE(1);
  STOLDS(0);
  __syncthreads();
  LOADG(k0 + 192);
  COMPUTE(0);
  STOLDS(1);
  __syncthreads();
  COMPUTE(1);
  __syncthreads();
#undef LOADG
#undef STOLDS
#undef COMPUTE

  // K-group partials -> split Gs planes, plain disjoint stores (no atomics).
  // C/D layout: col = lane&15, row = (lane>>4)*4 + reg.
  {
    const int crow = wid * 16 + (lane >> 4) * 4;
#pragma unroll
    for (int i = 0; i < 4; ++i) Gs[g][crow + i][lr] = acc0[i];
#pragma unroll
    for (int i = 0; i < 4; ++i) Gs[g][crow + i][16 + lr] = acc1[i];
  }
  __syncthreads();

  // Path-GCN layer-1 combine -> U (bf16). t == local row (tile == one batch).
  {
    const int rr = tid >> 3;
    const int c4 = (tid & 7) * 4;
    const int t = rr;
    const float is6 = 0.4082482904638630f;  // 1/sqrt(6)
    float c0, c1, c2, d1, d2, al, be;
    if (t <= 1) {
      c0 = 0.f; c1 = 0.f; c2 = 1.f; d1 = 0.f; d2 = 0.f; al = 1.f; be = 0.f;
    } else if (t == 2) {
      c0 = 0.f; c1 = 0.5f; c2 = 0.5f; d1 = 0.5f; d2 = 0.5f; al = 0.5f; be = 0.5f;
    } else {
      c0 = (t == 3) ? is6 : (1.f / 3.f);
      c1 = 1.f / 3.f; c2 = is6;
      d1 = is6; d2 = 0.5f;
      al = is6; be = 0.5f;
    }
    const int rm1 = (t >= 1) ? rr - 1 : rr;
    const int rm2 = (t >= 2) ? rr - 2 : rr;
    ushort4 uo;
    unsigned short* up = (unsigned short*)&uo;
#pragma unroll
    for (int j = 0; j < 4; ++j) {
      const int c = c4 + j;
      const float gc = Gs[0][rr][c] + Gs[1][rr][c];
      const float gb = Gs[0][rm1][c] + Gs[1][rm1][c];
      const float ga = Gs[0][rm2][c] + Gs[1][rm2][c];
      const float bb = b1[col0 + c];
      const float h1a = fmaxf(c0 * ga + c1 * gb + c2 * gc + bb, 0.f);
      const float h1b = fmaxf(d1 * gb + d2 * gc + bb, 0.f);
      up[j] = f2bf(al * h1a + be * h1b);
    }
    *reinterpret_cast<ushort4*>(&U[(size_t)(row0 + rr) * HH + col0 + c4]) = uo;
  }
}

// ---------------------------------------------------------------------------
// k2 [r16-verbatim, best measured]: fused GEMM2 + head, single staging round.
// 512 thr = 4 K-groups x 2 waves; group kg owns K-slice kg*128 as ONE chunk.
// Merge via 4 split tg planes + plain stores. Per block (ct 0..7, rt 0..31):
// tgt tile 32x32 = relu(sum planes + b2); head partial atomicAdd into out
// (zeroed by k1; bl added by ct==0). LDS = 94.9 KB.
// ---------------------------------------------------------------------------
__global__ __launch_bounds__(512) void k2_fused_head(
    const unsigned short* __restrict__ U, const unsigned short* __restrict__ W2t,
    const float* __restrict__ b2, const float* __restrict__ Wl,
    const float* __restrict__ bl, float* __restrict__ out) {
  __shared__ unsigned short As2[4][32][136];
  __shared__ unsigned short Bt2[4][32][136];
  __shared__ float tg[4][32][36];
  __shared__ float tgs[32][36];
  __shared__ float sWl[32][18];

  const int tid = threadIdx.x;
  const int lane = tid & 63;
  const int w = tid >> 6;
  const int kg = w >> 1;               // K-group 0..3
  const int wg = w & 1;                // wave in group: row-half
  const int gt = tid & 127;
  const int ct = blockIdx.x & 7;
  const int col0 = ct * 32;
  const int r0 = (blockIdx.x >> 3) * 32;
  const int lr = lane & 15, lk = (lane >> 4) * 8;
  const int k0 = kg * 128;

  const int sar = gt >> 2, sak = (gt & 3) * 32;

  // Stage Wl col-slice early (overlaps with global load latency).
  for (int i = tid; i < 32 * AA; i += 512) {
    const int n = i / AA, o = i - n * AA;
    sWl[n][o] = Wl[(size_t)(col0 + n) * AA + o];
  }

  // One staging round: 8 x bf16x8 global loads, all in flight together.
  bf16x8 pa[4], pb[4];
  {
    const unsigned short* Ap = &U[(size_t)(r0 + sar) * HH + k0 + sak];
#pragma unroll
    for (int q = 0; q < 4; ++q) pa[q] = *reinterpret_cast<const bf16x8*>(Ap + q * 8);
    const unsigned short* Bp = &W2t[(size_t)(col0 + sar) * HH + k0 + sak];
#pragma unroll
    for (int q = 0; q < 4; ++q) pb[q] = *reinterpret_cast<const bf16x8*>(Bp + q * 8);
  }
#pragma unroll
  for (int q = 0; q < 4; ++q)
    *reinterpret_cast<bf16x8*>(&As2[kg][sar][sak + q * 8]) = pa[q];
#pragma unroll
  for (int q = 0; q < 4; ++q)
    *reinterpret_cast<bf16x8*>(&Bt2[kg][sar][sak + q * 8]) = pb[q];
  __syncthreads();

  // Compute: wave (kg, wg) -> rows wg*16..+15, cols 0-15 (acc0) & 16-31 (acc1).
  f32x4 acc0 = {0.f, 0.f, 0.f, 0.f}, acc1 = {0.f, 0.f, 0.f, 0.f};
#pragma unroll
  for (int ks = 0; ks < 4; ++ks) {
    const bf16x8 af = *reinterpret_cast<const bf16x8*>(&As2[kg][wg * 16 + lr][ks * 32 + lk]);
    const bf16x8 bf0 = *reinterpret_cast<const bf16x8*>(&Bt2[kg][lr][ks * 32 + lk]);
    const bf16x8 bf1 = *reinterpret_cast<const bf16x8*>(&Bt2[kg][16 + lr][ks * 32 + lk]);
    acc0 = __builtin_amdgcn_mfma_f32_16x16x32_bf16(af, bf0, acc0, 0, 0, 0);
    acc1 = __builtin_amdgcn_mfma_f32_16x16x32_bf16(af, bf1, acc1, 0, 0, 0);
  }

  // Plane write: plain disjoint stores (C/D: col=lane&15, row=(lane>>4)*4+i).
  {
    const int crow = wg * 16 + (lane >> 4) * 4;
#pragma unroll
    for (int i = 0; i < 4; ++i) {
      tg[kg][crow + i][lr] = acc0[i];
      tg[kg][crow + i][16 + lr] = acc1[i];
    }
  }
  __syncthreads();

  // Sum 4 planes + b2 + relu -> tgs.
  for (int i = tid; i < 32 * 32; i += 512) {
    const int r = i >> 5, c = i & 31;
    const float s = tg[0][r][c] + tg[1][r][c] + tg[2][r][c] + tg[3][r][c]
                    + b2[col0 + c];
    tgs[r][c] = fmaxf(s, 0.f);
  }
  __syncthreads();

  // Head partial: out[r0+r][o] += sum_n tgs[r][n] * sWl[n][o] (+bl if ct==0).
  for (int p = tid; p < 32 * AA; p += 512) {
    const int r = p / AA, o = p - r * AA;
    float s = (ct == 0) ? bl[o] : 0.f;
#pragma unroll 8
    for (int n = 0; n < 32; ++n) s = fmaf(tgs[r][n], sWl[n][o], s);
    atomicAdd(&out[(size_t)(r0 + r) * AA + o], s);
  }
}

extern "C" void kernel_launch(void* const* d_in, const int* in_sizes, int n_in,
                              void* d_out, int out_size, void* d_ws, size_t ws_size,
                              hipStream_t stream) {
  const float* obs = (const float*)d_in[0];   // [1024, 512]
  const float* W1 = (const float*)d_in[4];    // [512, 512]
  const float* b1 = (const float*)d_in[5];    // [512]
  const float* W2 = (const float*)d_in[6];    // [512, 256]
  const float* b2 = (const float*)d_in[7];    // [256]
  const float* Wl = (const float*)d_in[8];    // [256, 18]
  const float* bl = (const float*)d_in[9];    // [18]
  float* out = (float*)d_out;                 // [1024, 18]

  unsigned short* U = (unsigned short*)d_ws;          // 1024x512 bf16 = 1 MiB
  unsigned short* W2t = U + (size_t)ROWS * HH;        // 256x512 bf16 = 256 KiB

  // 1) U = pathGCN1(obs @ W1) + {zero out, W2->W2t bf16}. 256 blocks.
  k1_mfma_combine<<<256, 512, 0, stream>>>(obs, W1, b1, W2, U, W2t, out);

  // 2) GEMM2 (4 K-groups, single staging round) + fused head. 256 blocks.
  k2_fused_head<<<256, 512, 0, stream>>>(U, W2t, b2, Wl, bl, out);
}

// Round 19
// 16.291 us; speedup vs baseline: 1.1465x; 1.0242x over previous
//
#include <hip/hip_runtime.h>

// Problem constants: B=16, T=64, N=128, D=512, H=512, O=256, A=18
#define DD 512
#define HH 512
#define OO 256
#define AA 18
#define ROWS 1024

typedef __attribute__((ext_vector_type(8))) short bf16x8;
typedef __attribute__((ext_vector_type(4))) float f32x4;

// f32 -> bf16 round-to-nearest-even (bit trick; inputs are finite).
__device__ __forceinline__ unsigned short f2bf(float x) {
  unsigned u = __builtin_bit_cast(unsigned, x);
  u += 0x7FFFu + ((u >> 16) & 1u);
  return (unsigned short)(u >> 16);
}

// ---------------------------------------------------------------------------
// k1: U(bf16) = pathGCN1(obs @ W1), SINGLE staging round (k2-r16-proven
// structure): 512 thr = 4 K-groups x 2 waves; group kg owns K-slice kg*128
// as ONE chunk. Per thread: 16 coalesced float4 A-loads + 8 coalesced
// float4 B-loads, one vmcnt drain, ONE staging barrier (was 4).
// Tile 64x32 (64 rows == one batch -> t == local row). Merge via 4 split
// Gs planes + plain stores (no LDS atomics). Prologue chores: zero
// out-slice + one W2 row -> bf16 W2t. Grid: 16 ct x 16 rt = 256 blocks.
// LDS: As 69632 + Bt 34816 + Gs 36864 = 138 KB (1 block/CU, grid == CUs).
// ---------------------------------------------------------------------------
__global__ __launch_bounds__(512) void k1_mfma_combine(
    const float* __restrict__ obs, const float* __restrict__ W1,
    const float* __restrict__ b1, const float* __restrict__ W2,
    unsigned short* __restrict__ U, unsigned short* __restrict__ W2t,
    float* __restrict__ out) {
  __shared__ unsigned short As[4][64][136];   // [K-group][row][k]
  __shared__ unsigned short Bt[4][32][136];   // [K-group][col][k]
  __shared__ float Gs[4][64][36];

  const int tid = threadIdx.x;
  const int blk = blockIdx.x;
  const int kg = tid >> 7;             // K-group 0..3
  const int gt = tid & 127;
  const int lane = tid & 63;
  const int wg = (tid >> 6) & 1;       // wave within group (row-half of 64)
  const int col0 = (blk & 15) * 32;
  const int row0 = (blk >> 4) * 64;
  const int k0 = kg * 128;

  // Prologue chore 1: zero out slice (256 blocks x 72 = 18432 = 1024*18).
  if (tid < 72) out[blk * 72 + tid] = 0.f;
  // Prologue chore 2: W2t[n=blk][k=tid] = bf16(W2[k][n]).
  W2t[(size_t)blk * HH + tid] = f2bf(W2[(size_t)tid * OO + blk]);

  const int lr = lane & 15, lk = (lane >> 4) * 8; // fragment indices

  // A staging map: flat float4 idx f = q*128 + gt over 64x128 f32 tile:
  //   row = q*4 + (gt>>5), c4 = gt&31  (lane-consecutive -> coalesced)
  const int ar = gt >> 5;          // row sub-offset 0..3
  const int ac4 = gt & 31;         // float4 k-slot
  // B staging map: f = q*128 + gt over 128x32 f32 tile:
  //   krow = q*16 + (gt>>3), c4 = gt&7
  const int bkr = gt >> 3;         // 0..15
  const int bc4 = gt & 7;

  // One staging round: 24 float4 loads, all in flight together.
  float4 pa[16], pb[8];
  {
    const float* Ab = &obs[(size_t)(row0 + ar) * DD + k0 + ac4 * 4];
#pragma unroll
    for (int q = 0; q < 16; ++q)
      pa[q] = *reinterpret_cast<const float4*>(Ab + (size_t)q * 4 * DD);
    const float* Bb = &W1[(size_t)(k0 + bkr) * HH + col0 + bc4 * 4];
#pragma unroll
    for (int q = 0; q < 8; ++q)
      pb[q] = *reinterpret_cast<const float4*>(Bb + (size_t)q * 16 * HH);
  }
#pragma unroll
  for (int q = 0; q < 16; ++q) {
    ushort4 v;
    v.x = f2bf(pa[q].x); v.y = f2bf(pa[q].y);
    v.z = f2bf(pa[q].z); v.w = f2bf(pa[q].w);
    *reinterpret_cast<ushort4*>(&As[kg][q * 4 + ar][ac4 * 4]) = v;
  }
#pragma unroll
  for (int q = 0; q < 8; ++q) {
    const int kk = q * 16 + bkr;
    Bt[kg][bc4 * 4 + 0][kk] = f2bf(pb[q].x);
    Bt[kg][bc4 * 4 + 1][kk] = f2bf(pb[q].y);
    Bt[kg][bc4 * 4 + 2][kk] = f2bf(pb[q].z);
    Bt[kg][bc4 * 4 + 3][kk] = f2bf(pb[q].w);
  }
  __syncthreads();

  // Compute: wave (kg, wg) -> rows wg*32..+31 (2 frags) x cols 0..31 (2 frags).
  f32x4 acc00 = {0.f, 0.f, 0.f, 0.f}, acc01 = {0.f, 0.f, 0.f, 0.f};
  f32x4 acc10 = {0.f, 0.f, 0.f, 0.f}, acc11 = {0.f, 0.f, 0.f, 0.f};
#pragma unroll
  for (int ks = 0; ks < 4; ++ks) {
    const bf16x8 a0 = *reinterpret_cast<const bf16x8*>(&As[kg][wg * 32 + lr][ks * 32 + lk]);
    const bf16x8 a1 = *reinterpret_cast<const bf16x8*>(&As[kg][wg * 32 + 16 + lr][ks * 32 + lk]);
    const bf16x8 b0 = *reinterpret_cast<const bf16x8*>(&Bt[kg][lr][ks * 32 + lk]);
    const bf16x8 b1 = *reinterpret_cast<const bf16x8*>(&Bt[kg][16 + lr][ks * 32 + lk]);
    acc00 = __builtin_amdgcn_mfma_f32_16x16x32_bf16(a0, b0, acc00, 0, 0, 0);
    acc01 = __builtin_amdgcn_mfma_f32_16x16x32_bf16(a0, b1, acc01, 0, 0, 0);
    acc10 = __builtin_amdgcn_mfma_f32_16x16x32_bf16(a1, b0, acc10, 0, 0, 0);
    acc11 = __builtin_amdgcn_mfma_f32_16x16x32_bf16(a1, b1, acc11, 0, 0, 0);
  }

  // Plane write: plain disjoint stores (C/D: col=lane&15, row=(lane>>4)*4+i).
  {
    const int crow = wg * 32 + (lane >> 4) * 4;
#pragma unroll
    for (int i = 0; i < 4; ++i) {
      Gs[kg][crow + i][lr] = acc00[i];
      Gs[kg][crow + i][16 + lr] = acc01[i];
      Gs[kg][crow + 16 + i][lr] = acc10[i];
      Gs[kg][crow + 16 + i][16 + lr] = acc11[i];
    }
  }
  __syncthreads();

  // Path-GCN layer-1 combine -> U (bf16). t == local row (tile == one batch).
  {
    const int rr = tid >> 3;
    const int c4 = (tid & 7) * 4;
    const int t = rr;
    const float is6 = 0.4082482904638630f;  // 1/sqrt(6)
    float c0, c1, c2, d1, d2, al, be;
    if (t <= 1) {
      c0 = 0.f; c1 = 0.f; c2 = 1.f; d1 = 0.f; d2 = 0.f; al = 1.f; be = 0.f;
    } else if (t == 2) {
      c0 = 0.f; c1 = 0.5f; c2 = 0.5f; d1 = 0.5f; d2 = 0.5f; al = 0.5f; be = 0.5f;
    } else {
      c0 = (t == 3) ? is6 : (1.f / 3.f);
      c1 = 1.f / 3.f; c2 = is6;
      d1 = is6; d2 = 0.5f;
      al = is6; be = 0.5f;
    }
    const int rm1 = (t >= 1) ? rr - 1 : rr;
    const int rm2 = (t >= 2) ? rr - 2 : rr;
    ushort4 uo;
    unsigned short* up = (unsigned short*)&uo;
#pragma unroll
    for (int j = 0; j < 4; ++j) {
      const int c = c4 + j;
      const float gc = (Gs[0][rr][c] + Gs[1][rr][c]) + (Gs[2][rr][c] + Gs[3][rr][c]);
      const float gb = (Gs[0][rm1][c] + Gs[1][rm1][c]) + (Gs[2][rm1][c] + Gs[3][rm1][c]);
      const float ga = (Gs[0][rm2][c] + Gs[1][rm2][c]) + (Gs[2][rm2][c] + Gs[3][rm2][c]);
      const float bb = b1[col0 + c];
      const float h1a = fmaxf(c0 * ga + c1 * gb + c2 * gc + bb, 0.f);
      const float h1b = fmaxf(d1 * gb + d2 * gc + bb, 0.f);
      up[j] = f2bf(al * h1a + be * h1b);
    }
    *reinterpret_cast<ushort4*>(&U[(size_t)(row0 + rr) * HH + col0 + c4]) = uo;
  }
}

// ---------------------------------------------------------------------------
// k2 [r16/r18-verbatim, best measured]: fused GEMM2 + head, single staging
// round. 512 thr = 4 K-groups x 2 waves; group kg owns K-slice kg*128 as ONE
// chunk. Merge via 4 split tg planes + plain stores. Per block (ct 0..7,
// rt 0..31): tgt tile 32x32 = relu(sum planes + b2); head partial atomicAdd
// into out (zeroed by k1; bl added by ct==0). LDS = 94.9 KB.
// ---------------------------------------------------------------------------
__global__ __launch_bounds__(512) void k2_fused_head(
    const unsigned short* __restrict__ U, const unsigned short* __restrict__ W2t,
    const float* __restrict__ b2, const float* __restrict__ Wl,
    const float* __restrict__ bl, float* __restrict__ out) {
  __shared__ unsigned short As2[4][32][136];
  __shared__ unsigned short Bt2[4][32][136];
  __shared__ float tg[4][32][36];
  __shared__ float tgs[32][36];
  __shared__ float sWl[32][18];

  const int tid = threadIdx.x;
  const int lane = tid & 63;
  const int w = tid >> 6;
  const int kg = w >> 1;               // K-group 0..3
  const int wg = w & 1;                // wave in group: row-half
  const int gt = tid & 127;
  const int ct = blockIdx.x & 7;
  const int col0 = ct * 32;
  const int r0 = (blockIdx.x >> 3) * 32;
  const int lr = lane & 15, lk = (lane >> 4) * 8;
  const int k0 = kg * 128;

  const int sar = gt >> 2, sak = (gt & 3) * 32;

  // Stage Wl col-slice early (overlaps with global load latency).
  for (int i = tid; i < 32 * AA; i += 512) {
    const int n = i / AA, o = i - n * AA;
    sWl[n][o] = Wl[(size_t)(col0 + n) * AA + o];
  }

  // One staging round: 8 x bf16x8 global loads, all in flight together.
  bf16x8 pa[4], pb[4];
  {
    const unsigned short* Ap = &U[(size_t)(r0 + sar) * HH + k0 + sak];
#pragma unroll
    for (int q = 0; q < 4; ++q) pa[q] = *reinterpret_cast<const bf16x8*>(Ap + q * 8);
    const unsigned short* Bp = &W2t[(size_t)(col0 + sar) * HH + k0 + sak];
#pragma unroll
    for (int q = 0; q < 4; ++q) pb[q] = *reinterpret_cast<const bf16x8*>(Bp + q * 8);
  }
#pragma unroll
  for (int q = 0; q < 4; ++q)
    *reinterpret_cast<bf16x8*>(&As2[kg][sar][sak + q * 8]) = pa[q];
#pragma unroll
  for (int q = 0; q < 4; ++q)
    *reinterpret_cast<bf16x8*>(&Bt2[kg][sar][sak + q * 8]) = pb[q];
  __syncthreads();

  // Compute: wave (kg, wg) -> rows wg*16..+15, cols 0-15 (acc0) & 16-31 (acc1).
  f32x4 acc0 = {0.f, 0.f, 0.f, 0.f}, acc1 = {0.f, 0.f, 0.f, 0.f};
#pragma unroll
  for (int ks = 0; ks < 4; ++ks) {
    const bf16x8 af = *reinterpret_cast<const bf16x8*>(&As2[kg][wg * 16 + lr][ks * 32 + lk]);
    const bf16x8 bf0 = *reinterpret_cast<const bf16x8*>(&Bt2[kg][lr][ks * 32 + lk]);
    const bf16x8 bf1 = *reinterpret_cast<const bf16x8*>(&Bt2[kg][16 + lr][ks * 32 + lk]);
    acc0 = __builtin_amdgcn_mfma_f32_16x16x32_bf16(af, bf0, acc0, 0, 0, 0);
    acc1 = __builtin_amdgcn_mfma_f32_16x16x32_bf16(af, bf1, acc1, 0, 0, 0);
  }

  // Plane write: plain disjoint stores (C/D: col=lane&15, row=(lane>>4)*4+i).
  {
    const int crow = wg * 16 + (lane >> 4) * 4;
#pragma unroll
    for (int i = 0; i < 4; ++i) {
      tg[kg][crow + i][lr] = acc0[i];
      tg[kg][crow + i][16 + lr] = acc1[i];
    }
  }
  __syncthreads();

  // Sum 4 planes + b2 + relu -> tgs.
  for (int i = tid; i < 32 * 32; i += 512) {
    const int r = i >> 5, c = i & 31;
    const float s = tg[0][r][c] + tg[1][r][c] + tg[2][r][c] + tg[3][r][c]
                    + b2[col0 + c];
    tgs[r][c] = fmaxf(s, 0.f);
  }
  __syncthreads();

  // Head partial: out[r0+r][o] += sum_n tgs[r][n] * sWl[n][o] (+bl if ct==0).
  for (int p = tid; p < 32 * AA; p += 512) {
    const int r = p / AA, o = p - r * AA;
    float s = (ct == 0) ? bl[o] : 0.f;
#pragma unroll 8
    for (int n = 0; n < 32; ++n) s = fmaf(tgs[r][n], sWl[n][o], s);
    atomicAdd(&out[(size_t)(r0 + r) * AA + o], s);
  }
}

extern "C" void kernel_launch(void* const* d_in, const int* in_sizes, int n_in,
                              void* d_out, int out_size, void* d_ws, size_t ws_size,
                              hipStream_t stream) {
  const float* obs = (const float*)d_in[0];   // [1024, 512]
  const float* W1 = (const float*)d_in[4];    // [512, 512]
  const float* b1 = (const float*)d_in[5];    // [512]
  const float* W2 = (const float*)d_in[6];    // [512, 256]
  const float* b2 = (const float*)d_in[7];    // [256]
  const float* Wl = (const float*)d_in[8];    // [256, 18]
  const float* bl = (const float*)d_in[9];    // [18]
  float* out = (float*)d_out;                 // [1024, 18]

  unsigned short* U = (unsigned short*)d_ws;          // 1024x512 bf16 = 1 MiB
  unsigned short* W2t = U + (size_t)ROWS * HH;        // 256x512 bf16 = 256 KiB

  // 1) U = pathGCN1(obs @ W1), single staging round + {zero out, W2->W2t}.
  k1_mfma_combine<<<256, 512, 0, stream>>>(obs, W1, b1, W2, U, W2t, out);

  // 2) GEMM2 (4 K-groups, single staging round) + fused head. 256 blocks.
  k2_fused_head<<<256, 512, 0, stream>>>(U, W2t, b2, Wl, bl, out);
}